// Round 3
// baseline (918.709 us; speedup 1.0000x reference)
//
#include <hip/hip_runtime.h>
#include <stdint.h>

#define N_NODES 50000
#define M_PAD   50048   // 391*128
#define R_REL   8
#define E_EDGES 100000
#define D_IN    768
#define D_H     256
#define N_CAT   2304    // 9*256 : [self | rel0..rel7]
#define LN_EPS  1e-5f

#define TILES_N 18      // N_CAT/128
#define TILES_M 391     // M_PAD/128
#define T_TOT   (TILES_N * TILES_M)          // 7038
#define T_PER_XCD ((T_TOT + 7) / 8)          // 880
#define NCHUNK  49      // ceil(50000/1024)
#define EP_STRIDE 68    // epilogue repack row stride (u16): bank-conflict-free

typedef __attribute__((ext_vector_type(8))) __bf16        bf16x8;
typedef __attribute__((ext_vector_type(4))) float         f32x4;
typedef __attribute__((ext_vector_type(8))) unsigned short u16x8;
typedef __attribute__((ext_vector_type(4))) unsigned short u16x4;
typedef __attribute__((ext_vector_type(4))) int            i32x4;

__device__ __forceinline__ float bf2f(unsigned short u) {
  union { float f; uint32_t i; } c; c.i = ((uint32_t)u) << 16; return c.f;
}
__device__ __forceinline__ unsigned short f2bf(float f) {
  uint32_t x = __float_as_uint(f);
  uint32_t r = (x + 0x7fffu + ((x >> 16) & 1u)) >> 16;   // RNE
  return (unsigned short)r;
}

__device__ __forceinline__ void gload_lds16(const void* g, uint32_t lds_off) {
  __builtin_amdgcn_global_load_lds(
      (const __attribute__((address_space(1))) void*)(uintptr_t)g,
      (__attribute__((address_space(3))) void*)(uintptr_t)lds_off, 16, 0, 0);
}

// ---------------- CSR build ----------------
__global__ void k_deg(const int* __restrict__ tgt, int* __restrict__ deg) {
  int e = blockIdx.x * 256 + threadIdx.x;
  if (e >= R_REL * E_EDGES) return;
  int r = e / E_EDGES;
  atomicAdd(&deg[r * N_NODES + tgt[e]], 1);
}

__global__ __launch_bounds__(256)
void k_scan1(const int* __restrict__ deg, int* __restrict__ rowptr,
             int* __restrict__ bsum) {
  __shared__ int wtot[4];
  const int r = blockIdx.y, chunk = blockIdx.x, tid = threadIdx.x;
  const int wave = tid >> 6, lane = tid & 63;
  const int i0 = chunk * 1024 + tid * 4;
  int v0 = 0, v1 = 0, v2 = 0, v3 = 0;
  const int* d = deg + r * N_NODES;
  if (chunk != NCHUNK - 1) {
    i32x4 v = *(const i32x4*)(d + i0);
    v0 = v[0]; v1 = v[1]; v2 = v[2]; v3 = v[3];
  } else {
    if (i0 + 0 < N_NODES) v0 = d[i0 + 0];
    if (i0 + 1 < N_NODES) v1 = d[i0 + 1];
    if (i0 + 2 < N_NODES) v2 = d[i0 + 2];
    if (i0 + 3 < N_NODES) v3 = d[i0 + 3];
  }
  const int tsum = v0 + v1 + v2 + v3;
  int inc = tsum;
#pragma unroll
  for (int off = 1; off < 64; off <<= 1) {
    int t = __shfl_up(inc, off, 64);
    if (lane >= off) inc += t;
  }
  if (lane == 63) wtot[wave] = inc;
  __syncthreads();
  int woff = 0;
#pragma unroll
  for (int w = 0; w < 4; ++w) woff += (w < wave) ? wtot[w] : 0;
  int excl = woff + inc - tsum;
  int* rp = rowptr + r * (N_NODES + 1);
  if (i0 + 0 < N_NODES) rp[i0 + 0] = excl;
  if (i0 + 1 < N_NODES) rp[i0 + 1] = excl + v0;
  if (i0 + 2 < N_NODES) rp[i0 + 2] = excl + v0 + v1;
  if (i0 + 3 < N_NODES) rp[i0 + 3] = excl + v0 + v1 + v2;
  if (tid == 0) bsum[r * NCHUNK + chunk] = wtot[0] + wtot[1] + wtot[2] + wtot[3];
}

__global__ __launch_bounds__(512)
void k_scan2(const int* __restrict__ bsum, int* __restrict__ chunkoff,
             int* __restrict__ rowptr) {
  const int r = threadIdx.x >> 6, lane = threadIdx.x & 63;
  int v = (lane < NCHUNK) ? bsum[r * NCHUNK + lane] : 0;
  int inc = v;
#pragma unroll
  for (int off = 1; off < 64; off <<= 1) {
    int t = __shfl_up(inc, off, 64);
    if (lane >= off) inc += t;
  }
  if (lane < NCHUNK) chunkoff[r * NCHUNK + lane] = inc - v;   // exclusive
  if (lane == NCHUNK - 1) rowptr[r * (N_NODES + 1) + N_NODES] = inc;
}

__global__ __launch_bounds__(256)
void k_scan3(const int* __restrict__ chunkoff, int* __restrict__ rowptr) {
  const int r = blockIdx.y, chunk = blockIdx.x;
  if (chunk == 0) return;
  const int off = chunkoff[r * NCHUNK + chunk];
  const int i0 = chunk * 1024 + threadIdx.x * 4;
  int* rp = rowptr + r * (N_NODES + 1);
#pragma unroll
  for (int j = 0; j < 4; ++j)
    if (i0 + j < N_NODES) rp[i0 + j] += off;
}

// per-node interleaved {start, count} table: sc[t*8+r]
__global__ void k_prep(const int* __restrict__ rowptr, const int* __restrict__ deg,
                       int2* __restrict__ sc) {
  int i = blockIdx.x * 256 + threadIdx.x;
  if (i >= N_NODES * 8) return;
  int t = i >> 3, r = i & 7;
  sc[i] = make_int2(rowptr[r * (N_NODES + 1) + t], deg[r * N_NODES + t]);
}

// fill CSR adjacency: e2[slot] = {src, bits(node_weight[src])}
__global__ void k_fill(const int* __restrict__ src, const int* __restrict__ tgt,
                       const float* __restrict__ nw, const int* __restrict__ rowptr,
                       int* __restrict__ cursor, int2* __restrict__ e2) {
  int e = blockIdx.x * 256 + threadIdx.x;
  if (e >= R_REL * E_EDGES) return;
  int r = e / E_EDGES;
  int t = tgt[e], s = src[e];
  int pos = atomicAdd(&cursor[r * N_NODES + t], 1);
  int slot = r * E_EDGES + rowptr[r * (N_NODES + 1) + t] + pos;
  e2[slot] = make_int2(s, __float_as_int(nw[s]));
}

// ---------------- conversions ----------------
__global__ void k_cvt_x(const float* __restrict__ x, unsigned short* __restrict__ xb) {
  const size_t i = ((size_t)blockIdx.x * 256 + threadIdx.x) * 4;
  if (i >= (size_t)N_NODES * D_IN) return;
  const f32x4 v = *(const f32x4*)(x + i);
  u16x4 o = { f2bf(v[0]), f2bf(v[1]), f2bf(v[2]), f2bf(v[3]) };
  *(u16x4*)(xb + i) = o;
}

// Wt[n][k] = n<256 ? Wself[k][n] : Wrel[(n-256)>>8][k][n&255]   (bf16, [N_CAT][K])
__global__ void k_cvt_w(const float* __restrict__ Ws, const float* __restrict__ Wr,
                        unsigned short* __restrict__ Wt, int K) {
  int idx = blockIdx.x * 256 + threadIdx.x;
  if (idx >= N_CAT * K) return;
  int n = idx / K, k = idx - n * K;
  float v = (n < 256) ? Ws[k * 256 + n]
                      : Wr[(size_t)((n - 256) >> 8) * K * 256 + k * 256 + (n & 255)];
  Wt[idx] = f2bf(v);
}

// ---------------- bf16 MFMA GEMM: C[M_PAD,N_CAT] = A[M_PAD,K] @ Bt[N_CAT,K]^T --------
__global__ __launch_bounds__(256, 2)
void k_gemm(const unsigned short* __restrict__ A, const unsigned short* __restrict__ Bt,
            unsigned short* __restrict__ C, int K) {
  const int tile = (blockIdx.x & 7) * T_PER_XCD + (blockIdx.x >> 3);
  if (tile >= T_TOT) return;
  const int tileM = (tile / TILES_N) * 128;
  const int tileN = (tile % TILES_N) * 128;

  __shared__ __align__(16) char smem[34816];   // 16K tiles; 34816 = 4 waves * 64*68*2 epilogue
  const int tid  = threadIdx.x;
  const int wave = tid >> 6, lane = tid & 63;
  const int wm = (wave >> 1) * 64, wn = (wave & 1) * 64;

  f32x4 acc[4][4] = {};

  const int srow = wave * 32 + (lane >> 2);
  const int kchunk = ((lane & 3) - ((lane >> 2) & 3)) & 3;   // content(r,s)=(s-r)&3
  const unsigned short* gA = A  + (size_t)(tileM + srow) * K + kchunk * 8;
  const unsigned short* gB = Bt + (size_t)(tileN + srow) * K + kchunk * 8;
  const uint32_t ldsA = (uint32_t)(uintptr_t)smem;
  const uint32_t ldsB = ldsA + 8192;
  const uint32_t lA0 = ldsA + (wave * 32) * 64;
  const uint32_t lB0 = ldsB + (wave * 32) * 64;
  const size_t rowstep = (size_t)16 * K;

  // fragment read: phase p=lane>>4 of row r reads slot (p+r)&3
  const int slot = (((lane >> 4) + (lane & 3)) & 3) * 16;
  const char* pA = smem        + (wm + (lane & 15)) * 64 + slot;
  const char* pB = smem + 8192 + (wn + (lane & 15)) * 64 + slot;

  const int nk = K >> 5;
  for (int kt = 0; kt < nk; ++kt) {
    const int koff = kt * 32;
    __syncthreads();
    gload_lds16(gA + koff,           lA0);
    gload_lds16(gA + rowstep + koff, lA0 + 16 * 64);
    gload_lds16(gB + koff,           lB0);
    gload_lds16(gB + rowstep + koff, lB0 + 16 * 64);
    __syncthreads();
    bf16x8 af[4], bfr[4];
#pragma unroll
    for (int i = 0; i < 4; ++i) af[i]  = *(const bf16x8*)(pA + i * 1024);
#pragma unroll
    for (int j = 0; j < 4; ++j) bfr[j] = *(const bf16x8*)(pB + j * 1024);
#pragma unroll
    for (int i = 0; i < 4; ++i)
#pragma unroll
      for (int j = 0; j < 4; ++j)
        acc[i][j] = __builtin_amdgcn_mfma_f32_16x16x32_bf16(af[i], bfr[j], acc[i][j], 0, 0, 0);
  }

  // epilogue: AGPR -> LDS (bf16, stride-68 u16 -> conflict-free) -> 16B global stores
  __syncthreads();                              // protect tile region from other waves
  unsigned short* st = (unsigned short*)smem + wave * (64 * EP_STRIDE);
  const int rq = (lane >> 4) * 4, cq = lane & 15;
#pragma unroll
  for (int i = 0; i < 4; ++i)
#pragma unroll
    for (int j = 0; j < 4; ++j)
#pragma unroll
      for (int p = 0; p < 4; ++p)
        st[(i * 16 + rq + p) * EP_STRIDE + j * 16 + cq] = f2bf(acc[i][j][p]);
  // wave-private region: no barrier needed (in-wave lgkmcnt ordering)
#pragma unroll
  for (int pass = 0; pass < 8; ++pass) {
    const int row = pass * 8 + (lane >> 3);
    const unsigned short* rp_ = st + row * EP_STRIDE + (lane & 7) * 8;
    u16x4 lo = *(const u16x4*)(rp_);
    u16x4 hi = *(const u16x4*)(rp_ + 4);
    u16x8 v = { lo[0], lo[1], lo[2], lo[3], hi[0], hi[1], hi[2], hi[3] };
    size_t off = (size_t)(tileM + wm + row) * N_CAT + tileN + wn + (lane & 7) * 8;
    *(u16x8*)(C + off) = v;
  }
}

// ---------------- fused gather + mean + self + bias + ReLU + LayerNorm ----------------
// one wave per node; 32-lane halves: 8 channels/lane, each half takes alternate edges.
// half0 seeds with self-row, half1 seeds with bias; combined via shfl_xor(32).
template <int FINAL>
__global__ __launch_bounds__(256)
void k_gather_ln(const unsigned short* __restrict__ Y, const int2* __restrict__ sc,
                 const int2* __restrict__ e2, const float* __restrict__ bias,
                 const float* __restrict__ g, const float* __restrict__ bln,
                 void* __restrict__ out) {
  const int wave = threadIdx.x >> 6, lane = threadIdx.x & 63;
  const int t = blockIdx.x * 4 + wave;
  if (t >= N_NODES) return;
  const int h = lane >> 5, sl = lane & 31;
  const int c0 = sl * 8;

  float a[8];
  if (h == 0) {
    u16x8 sv = *(const u16x8*)(Y + (size_t)t * N_CAT + c0);
#pragma unroll
    for (int i = 0; i < 8; ++i) a[i] = bf2f(sv[i]);
  } else {
    f32x4 b0 = *(const f32x4*)(bias + c0);
    f32x4 b1 = *(const f32x4*)(bias + c0 + 4);
    a[0] = b0[0]; a[1] = b0[1]; a[2] = b0[2]; a[3] = b0[3];
    a[4] = b1[0]; a[5] = b1[1]; a[6] = b1[2]; a[7] = b1[3];
  }

#pragma unroll
  for (int r = 0; r < R_REL; ++r) {
    const int2 s = sc[t * 8 + r];          // {start, cnt}, wave-uniform
    if (s.y == 0) continue;
    const int base = r * E_EDGES + s.x;
    const size_t colr = (size_t)(1 + r) * 256 + c0;
    float acc[8] = {0, 0, 0, 0, 0, 0, 0, 0};
    for (int idx = h; idx < s.y; idx += 2) {
      const int2 p = e2[base + idx];
      const float w = __int_as_float(p.y);
      u16x8 v = *(const u16x8*)(Y + (size_t)p.x * N_CAT + colr);
#pragma unroll
      for (int i = 0; i < 8; ++i) acc[i] += w * bf2f(v[i]);
    }
    const float inv = 1.0f / (float)s.y;
#pragma unroll
    for (int i = 0; i < 8; ++i) a[i] += inv * acc[i];
  }

  // combine halves; then both halves hold identical full sums
#pragma unroll
  for (int i = 0; i < 8; ++i) {
    a[i] += __shfl_xor(a[i], 32, 64);
    a[i] = fmaxf(a[i], 0.f);
  }
  float s1 = ((a[0] + a[1]) + (a[2] + a[3])) + ((a[4] + a[5]) + (a[6] + a[7]));
#pragma unroll
  for (int off = 16; off > 0; off >>= 1) s1 += __shfl_xor(s1, off, 64);
  const float mu = s1 * (1.f / 256.f);
  float d[8], s2 = 0.f;
#pragma unroll
  for (int i = 0; i < 8; ++i) { d[i] = a[i] - mu; s2 += d[i] * d[i]; }
#pragma unroll
  for (int off = 16; off > 0; off >>= 1) s2 += __shfl_xor(s2, off, 64);
  const float rs = rsqrtf(s2 * (1.f / 256.f) + LN_EPS);

  f32x4 g0 = *(const f32x4*)(g + c0);
  f32x4 g1 = *(const f32x4*)(g + c0 + 4);
  f32x4 l0 = *(const f32x4*)(bln + c0);
  f32x4 l1 = *(const f32x4*)(bln + c0 + 4);
  float o[8];
  o[0] = d[0] * rs * g0[0] + l0[0]; o[1] = d[1] * rs * g0[1] + l0[1];
  o[2] = d[2] * rs * g0[2] + l0[2]; o[3] = d[3] * rs * g0[3] + l0[3];
  o[4] = d[4] * rs * g1[0] + l1[0]; o[5] = d[5] * rs * g1[1] + l1[1];
  o[6] = d[6] * rs * g1[2] + l1[2]; o[7] = d[7] * rs * g1[3] + l1[3];

  if (h == 0) {
    if (FINAL) {
      float* op = (float*)out + (size_t)t * 256 + c0;
      f32x4 v0 = { o[0], o[1], o[2], o[3] };
      f32x4 v1 = { o[4], o[5], o[6], o[7] };
      *(f32x4*)(op) = v0;
      *(f32x4*)(op + 4) = v1;
    } else {
      u16x8 v = { f2bf(o[0]), f2bf(o[1]), f2bf(o[2]), f2bf(o[3]),
                  f2bf(o[4]), f2bf(o[5]), f2bf(o[6]), f2bf(o[7]) };
      *(u16x8*)((unsigned short*)out + (size_t)t * 256 + c0) = v;
    }
  }
}

// ---------------- launch ----------------
extern "C" void kernel_launch(void* const* d_in, const int* in_sizes, int n_in,
                              void* d_out, int out_size, void* d_ws, size_t ws_size,
                              hipStream_t stream) {
  (void)in_sizes; (void)n_in; (void)out_size; (void)ws_size;
  const float* x   = (const float*)d_in[0];
  const float* nw  = (const float*)d_in[1];
  const int*   esrc = (const int*)d_in[2];
  const int*   etgt = (const int*)d_in[3];
  const float* Wr0 = (const float*)d_in[4];
  const float* Ws0 = (const float*)d_in[5];
  const float* Wb0 = (const float*)d_in[6];
  const float* g0  = (const float*)d_in[7];
  const float* b0  = (const float*)d_in[8];
  const float* Wr1 = (const float*)d_in[9];
  const float* Ws1 = (const float*)d_in[10];
  const float* Wb1 = (const float*)d_in[11];
  const float* g1  = (const float*)d_in[12];
  const float* b1  = (const float*)d_in[13];

  char* p = (char*)d_ws;
  auto carve = [&](size_t bytes) {
    char* q = p;
    p += (bytes + 511) & ~(size_t)511;
    return q;
  };
  unsigned short* Y   = (unsigned short*)carve((size_t)M_PAD * N_CAT * 2);  // 230.6 MB
  unsigned short* xb  = (unsigned short*)carve((size_t)M_PAD * D_IN * 2);   //  76.9 MB
  unsigned short* h   = (unsigned short*)carve((size_t)M_PAD * D_H * 2);    //  25.6 MB
  unsigned short* Wt0 = (unsigned short*)carve((size_t)N_CAT * D_IN * 2);
  unsigned short* Wt1 = (unsigned short*)carve((size_t)N_CAT * D_H * 2);
  int*   deg     = (int*)carve((size_t)R_REL * N_NODES * 4);
  int*   cursor  = (int*)carve((size_t)R_REL * N_NODES * 4);
  int*   rowptr  = (int*)carve((size_t)R_REL * (N_NODES + 1) * 4);
  int*   bsum    = (int*)carve((size_t)R_REL * NCHUNK * 4);
  int*   chunkoff= (int*)carve((size_t)R_REL * NCHUNK * 4);
  int2*  e2      = (int2*)carve((size_t)R_REL * E_EDGES * 8);
  int2*  sc      = (int2*)carve((size_t)N_NODES * 8 * 8);

  // CSR build (shared by both layers)
  hipMemsetAsync(deg, 0, (size_t)R_REL * N_NODES * 4, stream);
  hipMemsetAsync(cursor, 0, (size_t)R_REL * N_NODES * 4, stream);
  k_deg<<<(R_REL * E_EDGES + 255) / 256, 256, 0, stream>>>(etgt, deg);
  k_scan1<<<dim3(NCHUNK, R_REL), 256, 0, stream>>>(deg, rowptr, bsum);
  k_scan2<<<1, 512, 0, stream>>>(bsum, chunkoff, rowptr);
  k_scan3<<<dim3(NCHUNK, R_REL), 256, 0, stream>>>(chunkoff, rowptr);
  k_prep<<<(N_NODES * 8 + 255) / 256, 256, 0, stream>>>(rowptr, deg, sc);
  k_fill<<<(R_REL * E_EDGES + 255) / 256, 256, 0, stream>>>(esrc, etgt, nw, rowptr,
                                                            cursor, e2);
  // conversions
  k_cvt_x<<<(N_NODES * D_IN / 4 + 255) / 256, 256, 0, stream>>>(x, xb);
  k_cvt_w<<<(N_CAT * D_IN + 255) / 256, 256, 0, stream>>>(Ws0, Wr0, Wt0, D_IN);
  k_cvt_w<<<(N_CAT * D_H + 255) / 256, 256, 0, stream>>>(Ws1, Wr1, Wt1, D_H);

  const int nblk = 8 * T_PER_XCD;   // 7040, XCD-swizzled in-kernel
  // layer 0
  k_gemm<<<nblk, 256, 0, stream>>>(xb, Wt0, Y, D_IN);
  k_gather_ln<0><<<N_NODES / 4, 256, 0, stream>>>(Y, sc, e2, Wb0, g0, b0, h);
  // layer 1
  k_gemm<<<nblk, 256, 0, stream>>>(h, Wt1, Y, D_H);
  k_gather_ln<1><<<N_NODES / 4, 256, 0, stream>>>(Y, sc, e2, Wb1, g1, b1, d_out);
}

// Round 4
// 797.760 us; speedup vs baseline: 1.1516x; 1.1516x over previous
//
#include <hip/hip_runtime.h>
#include <stdint.h>

#define N_NODES 50000
#define M_PAD   50048   // 391*128
#define R_REL   8
#define E_EDGES 100000
#define D_IN    768
#define D_H     256
#define N_CAT   2304    // 9*256 : [self | rel0..rel7]
#define LN_EPS  1e-5f

#define TILES_N 18      // N_CAT/128
#define TILES_M 391     // M_PAD/128
#define T_TOT   (TILES_N * TILES_M)          // 7038
#define T_PER_XCD ((T_TOT + 7) / 8)          // 880
#define NCHUNK  49      // ceil(50000/1024)
#define EP_STRIDE 68    // epilogue repack row stride (u16): bank-conflict-free
#define E_PAD_MAX 960000 // 800k edges + <=150k pad slots

typedef __attribute__((ext_vector_type(8))) __bf16        bf16x8;
typedef __attribute__((ext_vector_type(4))) float         f32x4;
typedef __attribute__((ext_vector_type(8))) unsigned short u16x8;
typedef __attribute__((ext_vector_type(4))) unsigned short u16x4;
typedef __attribute__((ext_vector_type(4))) int            i32x4;

__device__ __forceinline__ float bf2f(unsigned short u) {
  union { float f; uint32_t i; } c; c.i = ((uint32_t)u) << 16; return c.f;
}
__device__ __forceinline__ unsigned short f2bf(float f) {
  uint32_t x = __float_as_uint(f);
  uint32_t r = (x + 0x7fffu + ((x >> 16) & 1u)) >> 16;   // RNE
  return (unsigned short)r;
}

__device__ __forceinline__ void gload_lds16(const void* g, uint32_t lds_off) {
  __builtin_amdgcn_global_load_lds(
      (const __attribute__((address_space(1))) void*)(uintptr_t)g,
      (__attribute__((address_space(3))) void*)(uintptr_t)lds_off, 16, 0, 0);
}

// ---------------- CSR build (node-major, relations flattened) ----------------
__global__ void k_deg(const int* __restrict__ tgt, int* __restrict__ deg) {
  int e = blockIdx.x * 256 + threadIdx.x;
  if (e >= R_REL * E_EDGES) return;
  int r = e / E_EDGES;
  atomicAdd(&deg[r * N_NODES + tgt[e]], 1);
}

// per-node total degree, padded to multiple of 4
__global__ void k_ndeg(const int* __restrict__ deg, int* __restrict__ pdeg) {
  int t = blockIdx.x * 256 + threadIdx.x;
  if (t >= N_NODES) return;
  int s = 0;
#pragma unroll
  for (int r = 0; r < R_REL; ++r) s += deg[r * N_NODES + t];
  pdeg[t] = (s + 3) & ~3;
}

__global__ __launch_bounds__(256)
void k_scan1(const int* __restrict__ deg, int* __restrict__ rowptr,
             int* __restrict__ bsum) {
  __shared__ int wtot[4];
  const int chunk = blockIdx.x, tid = threadIdx.x;
  const int wave = tid >> 6, lane = tid & 63;
  const int i0 = chunk * 1024 + tid * 4;
  int v0 = 0, v1 = 0, v2 = 0, v3 = 0;
  const int* d = deg;
  if (chunk != NCHUNK - 1) {
    i32x4 v = *(const i32x4*)(d + i0);
    v0 = v[0]; v1 = v[1]; v2 = v[2]; v3 = v[3];
  } else {
    if (i0 + 0 < N_NODES) v0 = d[i0 + 0];
    if (i0 + 1 < N_NODES) v1 = d[i0 + 1];
    if (i0 + 2 < N_NODES) v2 = d[i0 + 2];
    if (i0 + 3 < N_NODES) v3 = d[i0 + 3];
  }
  const int tsum = v0 + v1 + v2 + v3;
  int inc = tsum;
#pragma unroll
  for (int off = 1; off < 64; off <<= 1) {
    int t = __shfl_up(inc, off, 64);
    if (lane >= off) inc += t;
  }
  if (lane == 63) wtot[wave] = inc;
  __syncthreads();
  int woff = 0;
#pragma unroll
  for (int w = 0; w < 4; ++w) woff += (w < wave) ? wtot[w] : 0;
  int excl = woff + inc - tsum;
  int* rp = rowptr;
  if (i0 + 0 < N_NODES) rp[i0 + 0] = excl;
  if (i0 + 1 < N_NODES) rp[i0 + 1] = excl + v0;
  if (i0 + 2 < N_NODES) rp[i0 + 2] = excl + v0 + v1;
  if (i0 + 3 < N_NODES) rp[i0 + 3] = excl + v0 + v1 + v2;
  if (tid == 0) bsum[chunk] = wtot[0] + wtot[1] + wtot[2] + wtot[3];
}

__global__ __launch_bounds__(64)
void k_scan2(const int* __restrict__ bsum, int* __restrict__ chunkoff,
             int* __restrict__ rowptr) {
  const int lane = threadIdx.x & 63;
  int v = (lane < NCHUNK) ? bsum[lane] : 0;
  int inc = v;
#pragma unroll
  for (int off = 1; off < 64; off <<= 1) {
    int t = __shfl_up(inc, off, 64);
    if (lane >= off) inc += t;
  }
  if (lane < NCHUNK) chunkoff[lane] = inc - v;   // exclusive
  if (lane == NCHUNK - 1) rowptr[N_NODES] = inc;
}

__global__ __launch_bounds__(256)
void k_scan3(const int* __restrict__ chunkoff, int* __restrict__ rowptr) {
  const int chunk = blockIdx.x;
  if (chunk == 0) return;
  const int off = chunkoff[chunk];
  const int i0 = chunk * 1024 + threadIdx.x * 4;
#pragma unroll
  for (int j = 0; j < 4; ++j)
    if (i0 + j < N_NODES) rowptr[i0 + j] += off;
}

// per-node {start, padded_count}
__global__ void k_prep(const int* __restrict__ nodeptr, int2* __restrict__ scN) {
  int t = blockIdx.x * 256 + threadIdx.x;
  if (t >= N_NODES) return;
  scN[t] = make_int2(nodeptr[t], nodeptr[t + 1] - nodeptr[t]);
}

// fill flattened adjacency: e2[slot] = {src | rel<<16, nw[src]/deg[rel][tgt]}
__global__ void k_fill(const int* __restrict__ src, const int* __restrict__ tgt,
                       const float* __restrict__ nw, const int* __restrict__ nodeptr,
                       const int* __restrict__ deg, int* __restrict__ cursor,
                       int2* __restrict__ e2) {
  int e = blockIdx.x * 256 + threadIdx.x;
  if (e >= R_REL * E_EDGES) return;
  int r = e / E_EDGES;
  int t = tgt[e], s = src[e];
  int pos = atomicAdd(&cursor[t], 1);
  int slot = nodeptr[t] + pos;
  float w = nw[s] / (float)deg[r * N_NODES + t];
  e2[slot] = make_int2(s | (r << 16), __float_as_int(w));
}

// ---------------- conversions ----------------
__global__ void k_cvt_x(const float* __restrict__ x, unsigned short* __restrict__ xb) {
  const size_t i = ((size_t)blockIdx.x * 256 + threadIdx.x) * 4;
  if (i >= (size_t)N_NODES * D_IN) return;
  const f32x4 v = *(const f32x4*)(x + i);
  u16x4 o = { f2bf(v[0]), f2bf(v[1]), f2bf(v[2]), f2bf(v[3]) };
  *(u16x4*)(xb + i) = o;
}

// Wt[n][k] = n<256 ? Wself[k][n] : Wrel[(n-256)>>8][k][n&255]   (bf16, [N_CAT][K])
__global__ void k_cvt_w(const float* __restrict__ Ws, const float* __restrict__ Wr,
                        unsigned short* __restrict__ Wt, int K) {
  int idx = blockIdx.x * 256 + threadIdx.x;
  if (idx >= N_CAT * K) return;
  int n = idx / K, k = idx - n * K;
  float v = (n < 256) ? Ws[k * 256 + n]
                      : Wr[(size_t)((n - 256) >> 8) * K * 256 + k * 256 + (n & 255)];
  Wt[idx] = f2bf(v);
}

// ---------------- bf16 MFMA GEMM, BK=64: C[M_PAD,N_CAT] = A @ Bt^T ----------------
// LDS rows are 128 B (8 x 16B chunks); slot s of row r holds chunk s^(r&7) -> both
// staging (wave-uniform base + lane*16) and fragment reads are conflict-free.
__global__ __launch_bounds__(256, 2)
void k_gemm(const unsigned short* __restrict__ A, const unsigned short* __restrict__ Bt,
            unsigned short* __restrict__ C, int K) {
  const int tile = (blockIdx.x & 7) * T_PER_XCD + (blockIdx.x >> 3);
  if (tile >= T_TOT) return;
  const int tileM = (tile / TILES_N) * 128;
  const int tileN = (tile % TILES_N) * 128;

  __shared__ __align__(16) char smem[34816];   // A 16K @0, B 16K @16384; epilogue 34816
  const int tid  = threadIdx.x;
  const int wave = tid >> 6, lane = tid & 63;
  const int wm = (wave >> 1) * 64, wn = (wave & 1) * 64;

  f32x4 acc[4][4] = {};

  // staging: call j covers rows j*32..j*32+31; wave w rows w*8+(l>>3); slot l&7
  const int rl = lane >> 3, sl8 = lane & 7;
  const int cch = sl8 ^ rl;                      // global chunk fetched by this lane
  const int srow = wave * 8 + rl;
  const unsigned short* gA = A  + (size_t)(tileM + srow) * K + cch * 8;
  const unsigned short* gB = Bt + (size_t)(tileN + srow) * K + cch * 8;
  const uint32_t ldsA = (uint32_t)(uintptr_t)smem;
  const uint32_t ldsB = ldsA + 16384;
  const uint32_t lA0 = ldsA + (wave * 8) * 128;
  const uint32_t lB0 = ldsB + (wave * 8) * 128;

  // fragment read bases: row stride 128B; chunk c=kk*4+p at slot c^(lane&7)
  const char* pAb = smem         + (wm + (lane & 15)) * 128;
  const char* pBb = smem + 16384 + (wn + (lane & 15)) * 128;
  const int fph = lane >> 4, x7 = lane & 7;

  const int nk = K >> 6;
  for (int kt = 0; kt < nk; ++kt) {
    const size_t koff = (size_t)kt * 64;
    __syncthreads();
#pragma unroll
    for (int j = 0; j < 4; ++j) {
      gload_lds16(gA + (size_t)j * 32 * K + koff, lA0 + j * 4096);
      gload_lds16(gB + (size_t)j * 32 * K + koff, lB0 + j * 4096);
    }
    __syncthreads();
#pragma unroll
    for (int kk = 0; kk < 2; ++kk) {
      const int sA = ((kk * 4 + fph) ^ x7) * 16;
      bf16x8 af[4], bfr[4];
#pragma unroll
      for (int i = 0; i < 4; ++i) af[i]  = *(const bf16x8*)(pAb + i * 2048 + sA);
#pragma unroll
      for (int j = 0; j < 4; ++j) bfr[j] = *(const bf16x8*)(pBb + j * 2048 + sA);
#pragma unroll
      for (int i = 0; i < 4; ++i)
#pragma unroll
        for (int j = 0; j < 4; ++j)
          acc[i][j] = __builtin_amdgcn_mfma_f32_16x16x32_bf16(af[i], bfr[j], acc[i][j], 0, 0, 0);
    }
  }

  // epilogue: AGPR -> LDS (bf16, stride-68 u16) -> 16B global stores
  __syncthreads();
  unsigned short* st = (unsigned short*)smem + wave * (64 * EP_STRIDE);
  const int rq = (lane >> 4) * 4, cq = lane & 15;
#pragma unroll
  for (int i = 0; i < 4; ++i)
#pragma unroll
    for (int j = 0; j < 4; ++j)
#pragma unroll
      for (int p = 0; p < 4; ++p)
        st[(i * 16 + rq + p) * EP_STRIDE + j * 16 + cq] = f2bf(acc[i][j][p]);
#pragma unroll
  for (int pass = 0; pass < 8; ++pass) {
    const int row = pass * 8 + (lane >> 3);
    const unsigned short* rp_ = st + row * EP_STRIDE + (lane & 7) * 8;
    u16x4 lo = *(const u16x4*)(rp_);
    u16x4 hi = *(const u16x4*)(rp_ + 4);
    u16x8 v = { lo[0], lo[1], lo[2], lo[3], hi[0], hi[1], hi[2], hi[3] };
    size_t off = (size_t)(tileM + wm + row) * N_CAT + tileN + wn + (lane & 7) * 8;
    *(u16x8*)(C + off) = v;
  }
}

// ---------------- fused gather + mean + self + bias + ReLU + LayerNorm ----------------
// one wave per node, 4 channels/lane; single flattened edge loop, 4 edges in flight.
template <int FINAL>
__global__ __launch_bounds__(256)
void k_gather_ln(const unsigned short* __restrict__ Y, const int2* __restrict__ scN,
                 const int2* __restrict__ e2, const float* __restrict__ bias,
                 const float* __restrict__ g, const float* __restrict__ bln,
                 void* __restrict__ out) {
  const int wave = threadIdx.x >> 6, lane = threadIdx.x & 63;
  const int t = blockIdx.x * 4 + wave;
  if (t >= N_NODES) return;
  const int c0 = lane * 4;

  float a0, a1, a2, a3;
  {
    u16x4 sv = *(const u16x4*)(Y + (size_t)t * N_CAT + c0);
    f32x4 bb = *(const f32x4*)(bias + c0);
    a0 = bf2f(sv[0]) + bb[0];
    a1 = bf2f(sv[1]) + bb[1];
    a2 = bf2f(sv[2]) + bb[2];
    a3 = bf2f(sv[3]) + bb[3];
  }

  const int2 s = scN[t];                    // {start, padded_cnt (x4)}
  const int2* ep = e2 + s.x;
  for (int idx = 0; idx < s.y; idx += 4) {
    const int2 p0 = ep[idx + 0];
    const int2 p1 = ep[idx + 1];
    const int2 p2 = ep[idx + 2];
    const int2 p3 = ep[idx + 3];
    // addr: Y + src*2304 + (rel+1)*256 + c0 ; pad slots are {0,w=0} -> add 0
    const unsigned short* y0 = Y + (size_t)(p0.x & 0xFFFF) * N_CAT + (((p0.x >> 16) + 1) << 8) + c0;
    const unsigned short* y1 = Y + (size_t)(p1.x & 0xFFFF) * N_CAT + (((p1.x >> 16) + 1) << 8) + c0;
    const unsigned short* y2 = Y + (size_t)(p2.x & 0xFFFF) * N_CAT + (((p2.x >> 16) + 1) << 8) + c0;
    const unsigned short* y3 = Y + (size_t)(p3.x & 0xFFFF) * N_CAT + (((p3.x >> 16) + 1) << 8) + c0;
    u16x4 v0 = *(const u16x4*)y0;
    u16x4 v1 = *(const u16x4*)y1;
    u16x4 v2 = *(const u16x4*)y2;
    u16x4 v3 = *(const u16x4*)y3;
    const float w0 = __int_as_float(p0.y), w1 = __int_as_float(p1.y);
    const float w2 = __int_as_float(p2.y), w3 = __int_as_float(p3.y);
    a0 += w0 * bf2f(v0[0]) + w1 * bf2f(v1[0]) + w2 * bf2f(v2[0]) + w3 * bf2f(v3[0]);
    a1 += w0 * bf2f(v0[1]) + w1 * bf2f(v1[1]) + w2 * bf2f(v2[1]) + w3 * bf2f(v3[1]);
    a2 += w0 * bf2f(v0[2]) + w1 * bf2f(v1[2]) + w2 * bf2f(v2[2]) + w3 * bf2f(v3[2]);
    a3 += w0 * bf2f(v0[3]) + w1 * bf2f(v1[3]) + w2 * bf2f(v2[3]) + w3 * bf2f(v3[3]);
  }

  a0 = fmaxf(a0, 0.f); a1 = fmaxf(a1, 0.f); a2 = fmaxf(a2, 0.f); a3 = fmaxf(a3, 0.f);

  float s1 = (a0 + a1) + (a2 + a3);
#pragma unroll
  for (int off = 32; off > 0; off >>= 1) s1 += __shfl_xor(s1, off, 64);
  const float mu = s1 * (1.f / 256.f);
  const float d0 = a0 - mu, d1 = a1 - mu, d2 = a2 - mu, d3 = a3 - mu;
  float s2 = (d0 * d0 + d1 * d1) + (d2 * d2 + d3 * d3);
#pragma unroll
  for (int off = 32; off > 0; off >>= 1) s2 += __shfl_xor(s2, off, 64);
  const float rs = rsqrtf(s2 * (1.f / 256.f) + LN_EPS);

  f32x4 gg = *(const f32x4*)(g + c0);
  f32x4 ll = *(const f32x4*)(bln + c0);
  const float o0 = d0 * rs * gg[0] + ll[0];
  const float o1 = d1 * rs * gg[1] + ll[1];
  const float o2 = d2 * rs * gg[2] + ll[2];
  const float o3 = d3 * rs * gg[3] + ll[3];
  if (FINAL) {
    f32x4 o = { o0, o1, o2, o3 };
    *(f32x4*)((float*)out + (size_t)t * 256 + c0) = o;
  } else {
    u16x4 o = { f2bf(o0), f2bf(o1), f2bf(o2), f2bf(o3) };
    *(u16x4*)((unsigned short*)out + (size_t)t * 256 + c0) = o;
  }
}

// ---------------- launch ----------------
extern "C" void kernel_launch(void* const* d_in, const int* in_sizes, int n_in,
                              void* d_out, int out_size, void* d_ws, size_t ws_size,
                              hipStream_t stream) {
  (void)in_sizes; (void)n_in; (void)out_size; (void)ws_size;
  const float* x   = (const float*)d_in[0];
  const float* nw  = (const float*)d_in[1];
  const int*   esrc = (const int*)d_in[2];
  const int*   etgt = (const int*)d_in[3];
  const float* Wr0 = (const float*)d_in[4];
  const float* Ws0 = (const float*)d_in[5];
  const float* Wb0 = (const float*)d_in[6];
  const float* g0  = (const float*)d_in[7];
  const float* b0  = (const float*)d_in[8];
  const float* Wr1 = (const float*)d_in[9];
  const float* Ws1 = (const float*)d_in[10];
  const float* Wb1 = (const float*)d_in[11];
  const float* g1  = (const float*)d_in[12];
  const float* b1  = (const float*)d_in[13];

  char* p = (char*)d_ws;
  auto carve = [&](size_t bytes) {
    char* q = p;
    p += (bytes + 511) & ~(size_t)511;
    return q;
  };
  unsigned short* Y   = (unsigned short*)carve((size_t)M_PAD * N_CAT * 2);  // 230.6 MB
  unsigned short* xb  = (unsigned short*)carve((size_t)M_PAD * D_IN * 2);   //  76.9 MB
  unsigned short* h   = (unsigned short*)carve((size_t)M_PAD * D_H * 2);    //  25.6 MB
  unsigned short* Wt0 = (unsigned short*)carve((size_t)N_CAT * D_IN * 2);
  unsigned short* Wt1 = (unsigned short*)carve((size_t)N_CAT * D_H * 2);
  int*   deg     = (int*)carve((size_t)R_REL * N_NODES * 4);
  int*   pdeg    = (int*)carve((size_t)N_NODES * 4);
  int*   cursor  = (int*)carve((size_t)N_NODES * 4);
  int*   nodeptr = (int*)carve((size_t)(N_NODES + 1) * 4);
  int*   bsum    = (int*)carve((size_t)NCHUNK * 4);
  int*   chunkoff= (int*)carve((size_t)NCHUNK * 4);
  int2*  e2      = (int2*)carve((size_t)E_PAD_MAX * 8);
  int2*  scN     = (int2*)carve((size_t)N_NODES * 8);

  // CSR build (node-major; shared by both layers)
  hipMemsetAsync(deg, 0, (size_t)R_REL * N_NODES * 4, stream);
  hipMemsetAsync(cursor, 0, (size_t)N_NODES * 4, stream);
  hipMemsetAsync(e2, 0, (size_t)E_PAD_MAX * 8, stream);   // pad slots -> {src0, w=0}
  k_deg<<<(R_REL * E_EDGES + 255) / 256, 256, 0, stream>>>(etgt, deg);
  k_ndeg<<<(N_NODES + 255) / 256, 256, 0, stream>>>(deg, pdeg);
  k_scan1<<<NCHUNK, 256, 0, stream>>>(pdeg, nodeptr, bsum);
  k_scan2<<<1, 64, 0, stream>>>(bsum, chunkoff, nodeptr);
  k_scan3<<<NCHUNK, 256, 0, stream>>>(chunkoff, nodeptr);
  k_prep<<<(N_NODES + 255) / 256, 256, 0, stream>>>(nodeptr, scN);
  k_fill<<<(R_REL * E_EDGES + 255) / 256, 256, 0, stream>>>(esrc, etgt, nw, nodeptr,
                                                            deg, cursor, e2);
  // conversions
  k_cvt_x<<<(N_NODES * D_IN / 4 + 255) / 256, 256, 0, stream>>>(x, xb);
  k_cvt_w<<<(N_CAT * D_IN + 255) / 256, 256, 0, stream>>>(Ws0, Wr0, Wt0, D_IN);
  k_cvt_w<<<(N_CAT * D_H + 255) / 256, 256, 0, stream>>>(Ws1, Wr1, Wt1, D_H);

  const int nblk = 8 * T_PER_XCD;   // 7040, XCD-swizzled in-kernel
  // layer 0
  k_gemm<<<nblk, 256, 0, stream>>>(xb, Wt0, Y, D_IN);
  k_gather_ln<0><<<N_NODES / 4, 256, 0, stream>>>(Y, scN, e2, Wb0, g0, b0, h);
  // layer 1
  k_gemm<<<nblk, 256, 0, stream>>>(h, Wt1, Y, D_H);
  k_gather_ln<1><<<N_NODES / 4, 256, 0, stream>>>(Y, scN, e2, Wb1, g1, b1, d_out);
}